// Round 11
// baseline (201.832 us; speedup 1.0000x reference)
//
#include <hip/hip_runtime.h>
#include <hip/hip_bf16.h>

typedef __attribute__((ext_vector_type(4))) float f32x4;

constexpr int BQ  = 4096;          // batch per view
constexpr int DD  = 128;           // dim
constexpr int N2  = 2 * BQ;        // 8192
constexpr int NCHK = 32;           // column chunks (256 cols each)
constexpr int NCT  = 4;            // 64-col tiles per chunk
// exp(s/T) = exp2(s * 2/ln2); pre-scale matrix by sqrt(2.8853900817779268)
constexpr float SQS = 1.6986433f;

// ---- kernel 1: fp32 -> fp8(e4m3) in MFMA-fragment order, keys, counters ----
// obF layout: frag(group,kk) = 64 lanes x 8 bytes at index (group*4+kk)*64+lane
// (long units). Lane l: row = group*16 + (l&15), k = kk*32 + (l>>4)*8 + j.
__global__ __launch_bounds__(256) void convert_k(const float* __restrict__ a,
        const float* __restrict__ b, const int* __restrict__ tgt,
        long* __restrict__ obF, int* __restrict__ key, int* __restrict__ ctrs)
{
    int t = blockIdx.x * 256 + threadIdx.x;          // 131072 threads
    if (t < 65) ctrs[t] = 0;                         // ctr[64] + ctr2
    int row = t >> 4, c8 = t & 15;
    const float* src = (row < BQ) ? (a + (size_t)row * DD + c8 * 8)
                                  : (b + (size_t)(row - BQ) * DD + c8 * 8);
    float4 v0 = reinterpret_cast<const float4*>(src)[0];
    float4 v1 = reinterpret_cast<const float4*>(src)[1];
    int lo = __builtin_amdgcn_cvt_pk_fp8_f32(v0.x * SQS, v0.y * SQS, 0, false);
    lo     = __builtin_amdgcn_cvt_pk_fp8_f32(v0.z * SQS, v0.w * SQS, lo, true);
    int hi = __builtin_amdgcn_cvt_pk_fp8_f32(v1.x * SQS, v1.y * SQS, 0, false);
    hi     = __builtin_amdgcn_cvt_pk_fp8_f32(v1.z * SQS, v1.w * SQS, hi, true);
    long v = (((long)hi) << 32) | (unsigned)lo;
    int frag = ((row >> 4) * 4 + (c8 >> 2)) * 64 + (c8 & 3) * 16 + (row & 15);
    obF[frag] = v;

    if (t < N2) {
        // excl(i,j) == (key[i]==key[j]) covers BOTH the pair mask and the
        // target mask (rowmod==colmod implies identical target).
        int tv = tgt[t & (BQ - 1)];
        key[t] = (tv == -1) ? (0x40000000 + (t & (BQ - 1))) : tv;
    }
}

// ---- kernel 2: fused fp8 Gram + exp + mask + row sums + fence-free finish --
// grid 2048 = 64 row-tiles x 32 chunks (256 cols); 256 thr = 4 waves (2x2).
// Wave tile 64x32 per ct, NCT=4. B from L2 with 2-deep ping-pong register
// prefetch; no hot-loop barriers. 2048 blocks -> up to 5 blocks/CU resident
// (launch_bounds(256,5), VGPR cap 102 > 84 used) to hide L2 latency.
// Finish: RELEASE counter bumps (no acquire-invalidate), RELAXED AGENT loads.
__global__ __launch_bounds__(256, 5) void simloss_main(
        const long* __restrict__ F8, const int* __restrict__ key,
        float* __restrict__ pf, float* __restrict__ png,
        int* __restrict__ ctr, int* __restrict__ ctr2,
        float* __restrict__ bpart, float* __restrict__ outp)
{
    __shared__ float rred[2][128][2];    // row partials across wc
    __shared__ int winflag;
    __shared__ float red2[2];

    const int tid  = threadIdx.x;
    const int lane = tid & 63;
    const int wid  = tid >> 6;
    const int wr   = wid >> 1;           // 0..1 (64-row half)
    const int wc   = wid & 1;            // 0..1 (32-col half)
    const int l15  = lane & 15;
    const int l4   = lane >> 4;

    // XCD swizzle: 2048 blocks; XCD x owns chunks 4x..4x+3 (128KB B slice)
    const int raw = blockIdx.x;
    const int bid = (raw & 7) * 256 + (raw >> 3);
    const int ch  = bid >> 6;            // 0..31
    const int rt  = bid & 63;            // 0..63
    const int rowbase = rt * 128;

    // A fragments: wave wr owns rows wr*64..wr*64+63 = groups rt*8+wr*4+m
    long af[4][4];
#pragma unroll
    for (int m = 0; m < 4; ++m)
#pragma unroll
        for (int kk = 0; kk < 4; ++kk)
            af[m][kk] = F8[((rt * 8 + wr * 4 + m) * 4 + kk) * 64 + lane];

    int rk[4][4];
#pragma unroll
    for (int m = 0; m < 4; ++m)
#pragma unroll
        for (int r = 0; r < 4; ++r)
            rk[m][r] = key[rowbase + wr * 64 + m * 16 + l4 * 4 + r];

    float fs[4][4] = {}, ns[4][4] = {};

    // B base: col = ch*256 + ct*64 + wc*32 + n*16 + l15; frag = group*4+kk
    const long* Bw = F8 + (size_t)(ch * 64 + wc * 8) * 64 + lane;
    const int*  kp = key + ch * 256 + wc * 32 + l15;

    auto loadB = [&](long bx[8], int ct) {
        const long* p = Bw + ct * 1024;
#pragma unroll
        for (int q = 0; q < 8; ++q) bx[q] = p[q * 64];
    };
    auto compute = [&](const long bx[8], int ct) {
        int ck0 = kp[ct * 64];
        int ck1 = kp[ct * 64 + 16];
        f32x4 acc[4][2] = {};
#pragma unroll
        for (int kk = 0; kk < 4; ++kk)
#pragma unroll
            for (int m = 0; m < 4; ++m) {
                acc[m][0] = __builtin_amdgcn_mfma_f32_16x16x32_fp8_fp8(
                    af[m][kk], bx[kk], acc[m][0], 0, 0, 0);
                acc[m][1] = __builtin_amdgcn_mfma_f32_16x16x32_fp8_fp8(
                    af[m][kk], bx[4 + kk], acc[m][1], 0, 0, 0);
            }
#pragma unroll
        for (int m = 0; m < 4; ++m)
#pragma unroll
            for (int r = 0; r < 4; ++r) {
                float e0 = __builtin_amdgcn_exp2f(acc[m][0][r]);
                float e1 = __builtin_amdgcn_exp2f(acc[m][1][r]);
                fs[m][r] += e0 + e1;
                ns[m][r] += ((rk[m][r] == ck0) ? 0.0f : e0)
                          + ((rk[m][r] == ck1) ? 0.0f : e1);
            }
    };

    long bA[8], bB[8];
    loadB(bA, 0);
#pragma unroll 1
    for (int ct = 0; ct < NCT; ct += 2) {
        loadB(bB, ct + 1);            // prefetch next tile during compute
        compute(bA, ct);
        if (ct + 2 < NCT) loadB(bA, ct + 2);
        compute(bB, ct + 1);
    }

    // reduce across the 16 column-lanes, combine wc halves via LDS
#pragma unroll
    for (int m = 0; m < 4; ++m)
#pragma unroll
        for (int r = 0; r < 4; ++r) {
            float f = fs[m][r], g = ns[m][r];
#pragma unroll
            for (int msk = 1; msk < 16; msk <<= 1) {
                f += __shfl_xor(f, msk);
                g += __shfl_xor(g, msk);
            }
            if (l15 == 0) {
                int rl = wr * 64 + m * 16 + l4 * 4 + r;
                rred[wc][rl][0] = f;
                rred[wc][rl][1] = g;
            }
        }
    __syncthreads();
    if (tid < 128) {
        // device-visible partial stores (coherence-point stores, no fence)
        __hip_atomic_store(&pf[ch * N2 + rowbase + tid],
                           rred[0][tid][0] + rred[1][tid][0],
                           __ATOMIC_RELAXED, __HIP_MEMORY_SCOPE_AGENT);
        __hip_atomic_store(&png[ch * N2 + rowbase + tid],
                           rred[0][tid][1] + rred[1][tid][1],
                           __ATOMIC_RELAXED, __HIP_MEMORY_SCOPE_AGENT);
    }
    __syncthreads();   // every wave drains vmcnt at barrier -> stores issued

    if (tid == 0) {
        int old = __hip_atomic_fetch_add(&ctr[rt], 1,
                      __ATOMIC_RELEASE, __HIP_MEMORY_SCOPE_AGENT);
        winflag = (old == NCHK - 1);
    }
    __syncthreads();
    if (!winflag) return;

    // ---- rt winner: row losses for this tile (fixed slot order) -----------
    float li = 0.f;
    if (tid < 128) {
        int row = rowbase + tid;
        float full = 0.f, ng = 0.f;
#pragma unroll
        for (int s = 0; s < NCHK; ++s) {
            full += __hip_atomic_load(&pf[s * N2 + row],
                        __ATOMIC_RELAXED, __HIP_MEMORY_SCOPE_AGENT);
            ng   += __hip_atomic_load(&png[s * N2 + row],
                        __ATOMIC_RELAXED, __HIP_MEMORY_SCOPE_AGENT);
        }
        float o1 = full - 0.9f * ng;           // (1 - tau+) = 0.9
        float o2 = full + 818.1f * ng;         // n*tau+ - (1-tau+)
        li = (__builtin_amdgcn_logf(o2) - __builtin_amdgcn_logf(o1))
             * 0.6931471805599453f;
    }
#pragma unroll
    for (int m = 1; m < 64; m <<= 1) li += __shfl_xor(li, m);
    if (lane == 0 && wid < 2) red2[wid] = li;
    __syncthreads();
    if (tid == 0) {
        __hip_atomic_store(&bpart[rt], red2[0] + red2[1],
                           __ATOMIC_RELAXED, __HIP_MEMORY_SCOPE_AGENT);
        int old2 = __hip_atomic_fetch_add(ctr2, 1,
                       __ATOMIC_RELEASE, __HIP_MEMORY_SCOPE_AGENT);
        winflag = (old2 == 63);
    }
    __syncthreads();
    if (!winflag) return;

    // ---- global winner: fixed-order 64-way sum -> mean ---------------------
    if (wid == 0) {
        float v = __hip_atomic_load(&bpart[lane],
                      __ATOMIC_RELAXED, __HIP_MEMORY_SCOPE_AGENT);
#pragma unroll
        for (int m = 1; m < 64; m <<= 1) v += __shfl_xor(v, m);
        if (lane == 0) outp[0] = v / (float)N2;
    }
}

extern "C" void kernel_launch(void* const* d_in, const int* in_sizes, int n_in,
                              void* d_out, int out_size, void* d_ws, size_t ws_size,
                              hipStream_t stream)
{
    const float* out1 = (const float*)d_in[0];
    const float* out2 = (const float*)d_in[1];
    // d_in[2] = out_m, unused by the loss math
    const int*   tgt  = (const int*)d_in[3];
    float* out = (float*)d_out;

    // ws: obF8 1MB | pf 1MB | png 1MB | key 32KB | ctr[64]+ctr2 | bpart[64]
    long*   obF  = (long*)d_ws;
    float*  pf   = (float*)((char*)d_ws + (1u << 20));
    float*  png  = (float*)((char*)d_ws + (2u << 20));
    int*    key  = (int*)  ((char*)d_ws + (3u << 20));
    int*    ctrs = (int*)  ((char*)d_ws + (3u << 20) + 32768);
    float*  bpart= (float*)((char*)d_ws + (3u << 20) + 32768 + 512);

    convert_k<<<512, 256, 0, stream>>>(out1, out2, tgt, obF, key, ctrs);
    simloss_main<<<2048, 256, 0, stream>>>(obF, key, pf, png,
                                           ctrs, ctrs + 64, bpart, out);
}

// Round 12
// 118.953 us; speedup vs baseline: 1.6967x; 1.6967x over previous
//
#include <hip/hip_runtime.h>
#include <hip/hip_bf16.h>

typedef __attribute__((ext_vector_type(4))) float f32x4;

constexpr int BQ  = 4096;          // batch per view
constexpr int DD  = 128;           // dim
constexpr int N2  = 2 * BQ;        // 8192
constexpr int NCHK = 32;           // column chunks (256 cols each)
constexpr int NCT  = 4;            // 64-col tiles per chunk
// exp(s/T) = exp2(s * 2/ln2); pre-scale matrix by sqrt(2.8853900817779268)
constexpr float SQS = 1.6986433f;

// ---- kernel 1: fp32 -> fp8(e4m3) in MFMA-fragment order, plus mask keys ----
// obF layout: frag(group,kk) = 64 lanes x 8 bytes at index (group*4+kk)*64+lane
// (long units). Lane l: row = group*16 + (l&15), k = kk*32 + (l>>4)*8 + j.
__global__ __launch_bounds__(256) void convert_k(const float* __restrict__ a,
        const float* __restrict__ b, const int* __restrict__ tgt,
        long* __restrict__ obF, int* __restrict__ key)
{
    int t = blockIdx.x * 256 + threadIdx.x;          // 131072 threads
    int row = t >> 4, c8 = t & 15;
    const float* src = (row < BQ) ? (a + (size_t)row * DD + c8 * 8)
                                  : (b + (size_t)(row - BQ) * DD + c8 * 8);
    float4 v0 = reinterpret_cast<const float4*>(src)[0];
    float4 v1 = reinterpret_cast<const float4*>(src)[1];
    int lo = __builtin_amdgcn_cvt_pk_fp8_f32(v0.x * SQS, v0.y * SQS, 0, false);
    lo     = __builtin_amdgcn_cvt_pk_fp8_f32(v0.z * SQS, v0.w * SQS, lo, true);
    int hi = __builtin_amdgcn_cvt_pk_fp8_f32(v1.x * SQS, v1.y * SQS, 0, false);
    hi     = __builtin_amdgcn_cvt_pk_fp8_f32(v1.z * SQS, v1.w * SQS, hi, true);
    long v = (((long)hi) << 32) | (unsigned)lo;
    int frag = ((row >> 4) * 4 + (c8 >> 2)) * 64 + (c8 & 3) * 16 + (row & 15);
    obF[frag] = v;

    if (t < N2) {
        // excl(i,j) == (key[i]==key[j]) covers BOTH the pair mask and the
        // target mask (rowmod==colmod implies identical target).
        int tv = tgt[t & (BQ - 1)];
        key[t] = (tv == -1) ? (0x40000000 + (t & (BQ - 1))) : tv;
    }
}

// ---- kernel 2: fused fp8 Gram + exp + mask + row sums ----------------------
// grid 2048 = 64 row-tiles x 32 chunks (256 cols); 256 thr = 4 waves (2x2).
// Wave tile 64x32 per ct, NCT=4. B read straight from L2 with a 2-deep
// ping-pong register prefetch; no barriers in the hot loop. launch_bounds
// (256,4) caps VGPR at 128 (uses ~84 -> NO spill), 6 blocks/CU resident.
__global__ __launch_bounds__(256, 4) void simloss_main(
        const long* __restrict__ F8, const int* __restrict__ key,
        float* __restrict__ pf, float* __restrict__ png)
{
    __shared__ float rred[2][128][2];    // row partials across wc

    const int tid  = threadIdx.x;
    const int lane = tid & 63;
    const int wid  = tid >> 6;
    const int wr   = wid >> 1;           // 0..1 (64-row half)
    const int wc   = wid & 1;            // 0..1 (32-col half)
    const int l15  = lane & 15;
    const int l4   = lane >> 4;

    // XCD swizzle: 2048 blocks; XCD x owns chunks 4x..4x+3 (128KB B slice)
    const int raw = blockIdx.x;
    const int bid = (raw & 7) * 256 + (raw >> 3);
    const int ch  = bid >> 6;            // 0..31
    const int rt  = bid & 63;            // 0..63
    const int rowbase = rt * 128;

    // A fragments: wave wr owns rows wr*64..wr*64+63 = groups rt*8+wr*4+m
    long af[4][4];
#pragma unroll
    for (int m = 0; m < 4; ++m)
#pragma unroll
        for (int kk = 0; kk < 4; ++kk)
            af[m][kk] = F8[((rt * 8 + wr * 4 + m) * 4 + kk) * 64 + lane];

    int rk[4][4];
#pragma unroll
    for (int m = 0; m < 4; ++m)
#pragma unroll
        for (int r = 0; r < 4; ++r)
            rk[m][r] = key[rowbase + wr * 64 + m * 16 + l4 * 4 + r];

    float fs[4][4] = {}, ns[4][4] = {};

    // B base: col = ch*256 + ct*64 + wc*32 + n*16 + l15; frag = group*4+kk
    const long* Bw = F8 + (size_t)(ch * 64 + wc * 8) * 64 + lane;
    const int*  kp = key + ch * 256 + wc * 32 + l15;

    auto loadB = [&](long bx[8], int ct) {
        const long* p = Bw + ct * 1024;
#pragma unroll
        for (int q = 0; q < 8; ++q) bx[q] = p[q * 64];
    };
    auto compute = [&](const long bx[8], int ct) {
        int ck0 = kp[ct * 64];
        int ck1 = kp[ct * 64 + 16];
        f32x4 acc[4][2] = {};
#pragma unroll
        for (int kk = 0; kk < 4; ++kk)
#pragma unroll
            for (int m = 0; m < 4; ++m) {
                acc[m][0] = __builtin_amdgcn_mfma_f32_16x16x32_fp8_fp8(
                    af[m][kk], bx[kk], acc[m][0], 0, 0, 0);
                acc[m][1] = __builtin_amdgcn_mfma_f32_16x16x32_fp8_fp8(
                    af[m][kk], bx[4 + kk], acc[m][1], 0, 0, 0);
            }
#pragma unroll
        for (int m = 0; m < 4; ++m)
#pragma unroll
            for (int r = 0; r < 4; ++r) {
                float e0 = __builtin_amdgcn_exp2f(acc[m][0][r]);
                float e1 = __builtin_amdgcn_exp2f(acc[m][1][r]);
                fs[m][r] += e0 + e1;
                ns[m][r] += ((rk[m][r] == ck0) ? 0.0f : e0)
                          + ((rk[m][r] == ck1) ? 0.0f : e1);
            }
    };

    long bA[8], bB[8];
    loadB(bA, 0);
#pragma unroll 1
    for (int ct = 0; ct < NCT; ct += 2) {
        loadB(bB, ct + 1);            // prefetch next tile during compute
        compute(bA, ct);
        if (ct + 2 < NCT) loadB(bA, ct + 2);
        compute(bB, ct + 1);
    }

    // reduce across the 16 column-lanes, combine wc halves via LDS
#pragma unroll
    for (int m = 0; m < 4; ++m)
#pragma unroll
        for (int r = 0; r < 4; ++r) {
            float f = fs[m][r], g = ns[m][r];
#pragma unroll
            for (int msk = 1; msk < 16; msk <<= 1) {
                f += __shfl_xor(f, msk);
                g += __shfl_xor(g, msk);
            }
            if (l15 == 0) {
                int rl = wr * 64 + m * 16 + l4 * 4 + r;
                rred[wc][rl][0] = f;
                rred[wc][rl][1] = g;
            }
        }
    __syncthreads();
    if (tid < 128) {
        pf [ch * N2 + rowbase + tid] = rred[0][tid][0] + rred[1][tid][0];
        png[ch * N2 + rowbase + tid] = rred[0][tid][1] + rred[1][tid][1];
    }
}

// ---- kernel 3: per-row loss + block partial -------------------------------
__global__ __launch_bounds__(256) void row_loss_k(
        const float* __restrict__ pf, const float* __restrict__ png,
        float* __restrict__ bpart)
{
    int row = blockIdx.x * 256 + threadIdx.x;
    float full = 0.f, ng = 0.f;
#pragma unroll
    for (int s = 0; s < NCHK; ++s) {
        full += pf[s * N2 + row];
        ng   += png[s * N2 + row];
    }
    float o1 = full - 0.9f * ng;                // (1 - tau+) = 0.9
    float o2 = full + 818.1f * ng;              // n*tau+ - (1-tau+) = 819 - 0.9
    float li = (__builtin_amdgcn_logf(o2) - __builtin_amdgcn_logf(o1)) * 0.6931471805599453f;

#pragma unroll
    for (int m = 1; m < 64; m <<= 1) li += __shfl_xor(li, m);
    __shared__ float red[4];
    if ((threadIdx.x & 63) == 0) red[threadIdx.x >> 6] = li;
    __syncthreads();
    if (threadIdx.x == 0) bpart[blockIdx.x] = red[0] + red[1] + red[2] + red[3];
}

// ---- kernel 4: final scalar ----------------------------------------------
__global__ void final_k(const float* __restrict__ bpart, float* __restrict__ out)
{
    int l = threadIdx.x;
    float v = (l < 32) ? bpart[l] : 0.f;
#pragma unroll
    for (int m = 1; m < 32; m <<= 1) v += __shfl_xor(v, m);
    if (l == 0) out[0] = v / (float)N2;
}

extern "C" void kernel_launch(void* const* d_in, const int* in_sizes, int n_in,
                              void* d_out, int out_size, void* d_ws, size_t ws_size,
                              hipStream_t stream)
{
    const float* out1 = (const float*)d_in[0];
    const float* out2 = (const float*)d_in[1];
    // d_in[2] = out_m, unused by the loss math
    const int*   tgt  = (const int*)d_in[3];
    float* out = (float*)d_out;

    // ws: obF8 1MB | pf 1MB | png 1MB | key 32KB | bpart 128B
    long*   obF  = (long*)d_ws;
    float*  pf   = (float*)((char*)d_ws + (1u << 20));
    float*  png  = (float*)((char*)d_ws + (2u << 20));
    int*    key  = (int*)  ((char*)d_ws + (3u << 20));
    float*  bpart= (float*)((char*)d_ws + (3u << 20) + 32768);

    convert_k<<<512, 256, 0, stream>>>(out1, out2, tgt, obF, key);
    simloss_main<<<2048, 256, 0, stream>>>(obF, key, pf, png);
    row_loss_k<<<N2 / 256, 256, 0, stream>>>(pf, png, bpart);
    final_k<<<1, 64, 0, stream>>>(bpart, out);
}

// Round 13
// 62.596 us; speedup vs baseline: 3.2244x; 1.9003x over previous
//
#include <hip/hip_runtime.h>
#include <hip/hip_bf16.h>

typedef __attribute__((ext_vector_type(4))) float f32x4;

constexpr int BQ  = 4096;          // batch per view
constexpr int DD  = 128;           // dim
constexpr int N2  = 2 * BQ;        // 8192
constexpr int NCHK = 32;           // column chunks (256 cols each)
constexpr int NCT  = 4;            // 64-col tiles per chunk
// exp(s/T) = exp2(s * 2/ln2); pre-scale matrix by sqrt(2.8853900817779268)
constexpr float SQS = 1.6986433f;

// ---- kernel 1: fp32 -> fp8(e4m3) in MFMA-fragment order, plus mask keys ----
// obF layout: frag(group,kk) = 64 lanes x 8 bytes at index (group*4+kk)*64+lane
// (long units). Lane l: row = group*16 + (l&15), k = kk*32 + (l>>4)*8 + j.
__global__ __launch_bounds__(256) void convert_k(const float* __restrict__ a,
        const float* __restrict__ b, const int* __restrict__ tgt,
        long* __restrict__ obF, int* __restrict__ key)
{
    int t = blockIdx.x * 256 + threadIdx.x;          // 131072 threads
    int row = t >> 4, c8 = t & 15;
    const float* src = (row < BQ) ? (a + (size_t)row * DD + c8 * 8)
                                  : (b + (size_t)(row - BQ) * DD + c8 * 8);
    float4 v0 = reinterpret_cast<const float4*>(src)[0];
    float4 v1 = reinterpret_cast<const float4*>(src)[1];
    int lo = __builtin_amdgcn_cvt_pk_fp8_f32(v0.x * SQS, v0.y * SQS, 0, false);
    lo     = __builtin_amdgcn_cvt_pk_fp8_f32(v0.z * SQS, v0.w * SQS, lo, true);
    int hi = __builtin_amdgcn_cvt_pk_fp8_f32(v1.x * SQS, v1.y * SQS, 0, false);
    hi     = __builtin_amdgcn_cvt_pk_fp8_f32(v1.z * SQS, v1.w * SQS, hi, true);
    long v = (((long)hi) << 32) | (unsigned)lo;
    int frag = ((row >> 4) * 4 + (c8 >> 2)) * 64 + (c8 & 3) * 16 + (row & 15);
    obF[frag] = v;

    if (t < N2) {
        // excl(i,j) == (key[i]==key[j]) covers BOTH the pair mask and the
        // target mask (rowmod==colmod implies identical target).
        int tv = tgt[t & (BQ - 1)];
        key[t] = (tv == -1) ? (0x40000000 + (t & (BQ - 1))) : tv;
    }
}

// ---- kernel 2: fused fp8 Gram + exp + mask + row sums ----------------------
// grid 2048 = 64 row-tiles x 32 chunks (256 cols); 256 thr = 4 waves (2x2).
// Wave tile 64x32 per ct, NCT=4. B read straight from L2 with a 2-deep
// ping-pong register prefetch; no barriers in the hot loop.
// launch_bounds(256,3): unified VGPR+AGPR demand is ~148 (84 arch + 64 acc);
// cap 170 fits with ZERO spill (rounds 11/12 capped at 102/128 -> spill storm).
// Occupancy comes from the 2048-block grid: 3 blocks/CU resident.
__global__ __launch_bounds__(256, 3) void simloss_main(
        const long* __restrict__ F8, const int* __restrict__ key,
        float* __restrict__ pf, float* __restrict__ png)
{
    __shared__ float rred[2][128][2];    // row partials across wc

    const int tid  = threadIdx.x;
    const int lane = tid & 63;
    const int wid  = tid >> 6;
    const int wr   = wid >> 1;           // 0..1 (64-row half)
    const int wc   = wid & 1;            // 0..1 (32-col half)
    const int l15  = lane & 15;
    const int l4   = lane >> 4;

    // XCD swizzle: 2048 blocks; XCD x owns chunks 4x..4x+3 (128KB B slice)
    const int raw = blockIdx.x;
    const int bid = (raw & 7) * 256 + (raw >> 3);
    const int ch  = bid >> 6;            // 0..31
    const int rt  = bid & 63;            // 0..63
    const int rowbase = rt * 128;

    // A fragments: wave wr owns rows wr*64..wr*64+63 = groups rt*8+wr*4+m
    long af[4][4];
#pragma unroll
    for (int m = 0; m < 4; ++m)
#pragma unroll
        for (int kk = 0; kk < 4; ++kk)
            af[m][kk] = F8[((rt * 8 + wr * 4 + m) * 4 + kk) * 64 + lane];

    int rk[4][4];
#pragma unroll
    for (int m = 0; m < 4; ++m)
#pragma unroll
        for (int r = 0; r < 4; ++r)
            rk[m][r] = key[rowbase + wr * 64 + m * 16 + l4 * 4 + r];

    float fs[4][4] = {}, ns[4][4] = {};

    // B base: col = ch*256 + ct*64 + wc*32 + n*16 + l15; frag = group*4+kk
    const long* Bw = F8 + (size_t)(ch * 64 + wc * 8) * 64 + lane;
    const int*  kp = key + ch * 256 + wc * 32 + l15;

    auto loadB = [&](long bx[8], int ct) {
        const long* p = Bw + ct * 1024;
#pragma unroll
        for (int q = 0; q < 8; ++q) bx[q] = p[q * 64];
    };
    auto compute = [&](const long bx[8], int ct) {
        int ck0 = kp[ct * 64];
        int ck1 = kp[ct * 64 + 16];
        f32x4 acc[4][2] = {};
#pragma unroll
        for (int kk = 0; kk < 4; ++kk)
#pragma unroll
            for (int m = 0; m < 4; ++m) {
                acc[m][0] = __builtin_amdgcn_mfma_f32_16x16x32_fp8_fp8(
                    af[m][kk], bx[kk], acc[m][0], 0, 0, 0);
                acc[m][1] = __builtin_amdgcn_mfma_f32_16x16x32_fp8_fp8(
                    af[m][kk], bx[4 + kk], acc[m][1], 0, 0, 0);
            }
#pragma unroll
        for (int m = 0; m < 4; ++m)
#pragma unroll
            for (int r = 0; r < 4; ++r) {
                float e0 = __builtin_amdgcn_exp2f(acc[m][0][r]);
                float e1 = __builtin_amdgcn_exp2f(acc[m][1][r]);
                fs[m][r] += e0 + e1;
                ns[m][r] += ((rk[m][r] == ck0) ? 0.0f : e0)
                          + ((rk[m][r] == ck1) ? 0.0f : e1);
            }
    };

    long bA[8], bB[8];
    loadB(bA, 0);
#pragma unroll 1
    for (int ct = 0; ct < NCT; ct += 2) {
        loadB(bB, ct + 1);            // prefetch next tile during compute
        compute(bA, ct);
        if (ct + 2 < NCT) loadB(bA, ct + 2);
        compute(bB, ct + 1);
    }

    // reduce across the 16 column-lanes, combine wc halves via LDS
#pragma unroll
    for (int m = 0; m < 4; ++m)
#pragma unroll
        for (int r = 0; r < 4; ++r) {
            float f = fs[m][r], g = ns[m][r];
#pragma unroll
            for (int msk = 1; msk < 16; msk <<= 1) {
                f += __shfl_xor(f, msk);
                g += __shfl_xor(g, msk);
            }
            if (l15 == 0) {
                int rl = wr * 64 + m * 16 + l4 * 4 + r;
                rred[wc][rl][0] = f;
                rred[wc][rl][1] = g;
            }
        }
    __syncthreads();
    if (tid < 128) {
        pf [ch * N2 + rowbase + tid] = rred[0][tid][0] + rred[1][tid][0];
        png[ch * N2 + rowbase + tid] = rred[0][tid][1] + rred[1][tid][1];
    }
}

// ---- kernel 3: per-row loss + block partial -------------------------------
__global__ __launch_bounds__(256) void row_loss_k(
        const float* __restrict__ pf, const float* __restrict__ png,
        float* __restrict__ bpart)
{
    int row = blockIdx.x * 256 + threadIdx.x;
    float full = 0.f, ng = 0.f;
#pragma unroll
    for (int s = 0; s < NCHK; ++s) {
        full += pf[s * N2 + row];
        ng   += png[s * N2 + row];
    }
    float o1 = full - 0.9f * ng;                // (1 - tau+) = 0.9
    float o2 = full + 818.1f * ng;              // n*tau+ - (1-tau+) = 819 - 0.9
    float li = (__builtin_amdgcn_logf(o2) - __builtin_amdgcn_logf(o1)) * 0.6931471805599453f;

#pragma unroll
    for (int m = 1; m < 64; m <<= 1) li += __shfl_xor(li, m);
    __shared__ float red[4];
    if ((threadIdx.x & 63) == 0) red[threadIdx.x >> 6] = li;
    __syncthreads();
    if (threadIdx.x == 0) bpart[blockIdx.x] = red[0] + red[1] + red[2] + red[3];
}

// ---- kernel 4: final scalar ----------------------------------------------
__global__ void final_k(const float* __restrict__ bpart, float* __restrict__ out)
{
    int l = threadIdx.x;
    float v = (l < 32) ? bpart[l] : 0.f;
#pragma unroll
    for (int m = 1; m < 32; m <<= 1) v += __shfl_xor(v, m);
    if (l == 0) out[0] = v / (float)N2;
}

extern "C" void kernel_launch(void* const* d_in, const int* in_sizes, int n_in,
                              void* d_out, int out_size, void* d_ws, size_t ws_size,
                              hipStream_t stream)
{
    const float* out1 = (const float*)d_in[0];
    const float* out2 = (const float*)d_in[1];
    // d_in[2] = out_m, unused by the loss math
    const int*   tgt  = (const int*)d_in[3];
    float* out = (float*)d_out;

    // ws: obF8 1MB | pf 1MB | png 1MB | key 32KB | bpart 128B
    long*   obF  = (long*)d_ws;
    float*  pf   = (float*)((char*)d_ws + (1u << 20));
    float*  png  = (float*)((char*)d_ws + (2u << 20));
    int*    key  = (int*)  ((char*)d_ws + (3u << 20));
    float*  bpart= (float*)((char*)d_ws + (3u << 20) + 32768);

    convert_k<<<512, 256, 0, stream>>>(out1, out2, tgt, obF, key);
    simloss_main<<<2048, 256, 0, stream>>>(obF, key, pf, png);
    row_loss_k<<<N2 / 256, 256, 0, stream>>>(pf, png, bpart);
    final_k<<<1, 64, 0, stream>>>(bpart, out);
}

// Round 14
// 41.072 us; speedup vs baseline: 4.9140x; 1.5240x over previous
//
#include <hip/hip_runtime.h>
#include <hip/hip_bf16.h>

typedef __attribute__((ext_vector_type(4))) float f32x4;

constexpr int BQ  = 4096;          // batch per view
constexpr int DD  = 128;           // dim
constexpr int N2  = 2 * BQ;        // 8192
constexpr int NCHK = 16;           // column chunks (512 cols each)
constexpr int NCT  = 16;           // 32-col tiles per chunk
// exp(s/T) = exp2(s * 2/ln2); pre-scale matrix by sqrt(2.8853900817779268)
constexpr float SQS = 1.6986433f;

// ---- kernel 1: fp32 -> fp8(e4m3) in MFMA-fragment order, plus mask keys ----
// obF layout: frag(group,kk) = 64 lanes x 8 bytes at index (group*4+kk)*64+lane
// (long units). Lane l: row = group*16 + (l&15), k = kk*32 + (l>>4)*8 + j.
__global__ __launch_bounds__(256) void convert_k(const float* __restrict__ a,
        const float* __restrict__ b, const int* __restrict__ tgt,
        long* __restrict__ obF, int* __restrict__ key)
{
    int t = blockIdx.x * 256 + threadIdx.x;          // 131072 threads
    int row = t >> 4, c8 = t & 15;
    const float* src = (row < BQ) ? (a + (size_t)row * DD + c8 * 8)
                                  : (b + (size_t)(row - BQ) * DD + c8 * 8);
    float4 v0 = reinterpret_cast<const float4*>(src)[0];
    float4 v1 = reinterpret_cast<const float4*>(src)[1];
    int lo = __builtin_amdgcn_cvt_pk_fp8_f32(v0.x * SQS, v0.y * SQS, 0, false);
    lo     = __builtin_amdgcn_cvt_pk_fp8_f32(v0.z * SQS, v0.w * SQS, lo, true);
    int hi = __builtin_amdgcn_cvt_pk_fp8_f32(v1.x * SQS, v1.y * SQS, 0, false);
    hi     = __builtin_amdgcn_cvt_pk_fp8_f32(v1.z * SQS, v1.w * SQS, hi, true);
    long v = (((long)hi) << 32) | (unsigned)lo;
    int frag = ((row >> 4) * 4 + (c8 >> 2)) * 64 + (c8 & 3) * 16 + (row & 15);
    obF[frag] = v;

    if (t < N2) {
        // excl(i,j) == (key[i]==key[j]) covers BOTH the pair mask and the
        // target mask (rowmod==colmod implies identical target).
        int tv = tgt[t & (BQ - 1)];
        key[t] = (tv == -1) ? (0x40000000 + (t & (BQ - 1))) : tv;
    }
}

// ---- kernel 2: fused fp8 Gram + exp + mask + row sums ----------------------
// grid 1024 = 64 row-tiles x 16 chunks (512 cols); 256 thr = 4 waves stacked
// by rows (wave w owns rows rt*128 + w*32 .. +32). Wave tile 32x32 per ct.
// ~100 unified regs/wave -> fits the <=128 allocation granule -> 4 waves/SIMD
// (R8-R13 sat at 148 regs -> 256-granule -> 2 waves/SIMD, latency-bound).
// No LDS, no barriers: waves own disjoint rows; B straight from L2 with
// 2-deep ping-pong register prefetch. Grid = exactly 4 blocks/CU, no tail.
__global__ __launch_bounds__(256, 4) void simloss_main(
        const long* __restrict__ F8, const int* __restrict__ key,
        float* __restrict__ pf, float* __restrict__ png)
{
    const int tid  = threadIdx.x;
    const int lane = tid & 63;
    const int wr   = tid >> 6;           // 0..3: 32-row strip
    const int l15  = lane & 15;
    const int l4   = lane >> 4;

    // XCD swizzle: 1024 blocks; XCD x owns chunks {2x, 2x+1} (128KB B slice)
    const int raw = blockIdx.x;
    const int bid = (raw & 7) * 128 + (raw >> 3);
    const int ch  = bid >> 6;            // 0..15
    const int rt  = bid & 63;            // 0..63
    const int rowbase = rt * 128;

    // A fragments: wave wr owns rows rowbase + wr*32.. = groups rt*8 + wr*2 + m
    long af[2][4];
#pragma unroll
    for (int m = 0; m < 2; ++m)
#pragma unroll
        for (int kk = 0; kk < 4; ++kk)
            af[m][kk] = F8[((rt * 8 + wr * 2 + m) * 4 + kk) * 64 + lane];

    int rk[2][4];
#pragma unroll
    for (int m = 0; m < 2; ++m)
#pragma unroll
        for (int r = 0; r < 4; ++r)
            rk[m][r] = key[rowbase + wr * 32 + m * 16 + l4 * 4 + r];

    float fs[2][4] = {}, ns[2][4] = {};

    // B: col group g = ch*32 + ct*2 + n; frag idx (g*4+kk)*64+lane
    const long* Bw = F8 + (size_t)ch * 8192 + lane;
    const int*  kp = key + ch * 512 + l15;

    auto loadB = [&](long bx[8], int ct) {
        const long* p = Bw + ct * 512;
#pragma unroll
        for (int q = 0; q < 8; ++q) bx[q] = p[q * 64];
    };
    auto compute = [&](const long bx[8], int ct) {
        int ck0 = kp[ct * 32];
        int ck1 = kp[ct * 32 + 16];
        f32x4 acc[2][2] = {};
#pragma unroll
        for (int kk = 0; kk < 4; ++kk)
#pragma unroll
            for (int m = 0; m < 2; ++m) {
                acc[m][0] = __builtin_amdgcn_mfma_f32_16x16x32_fp8_fp8(
                    af[m][kk], bx[kk], acc[m][0], 0, 0, 0);
                acc[m][1] = __builtin_amdgcn_mfma_f32_16x16x32_fp8_fp8(
                    af[m][kk], bx[4 + kk], acc[m][1], 0, 0, 0);
            }
#pragma unroll
        for (int m = 0; m < 2; ++m)
#pragma unroll
            for (int r = 0; r < 4; ++r) {
                float e0 = __builtin_amdgcn_exp2f(acc[m][0][r]);
                float e1 = __builtin_amdgcn_exp2f(acc[m][1][r]);
                fs[m][r] += e0 + e1;
                ns[m][r] += ((rk[m][r] == ck0) ? 0.0f : e0)
                          + ((rk[m][r] == ck1) ? 0.0f : e1);
            }
    };

    long bA[8], bB[8];
    loadB(bA, 0);
#pragma unroll 1
    for (int ct = 0; ct < NCT; ct += 2) {
        loadB(bB, ct + 1);            // prefetch next tile during compute
        compute(bA, ct);
        if (ct + 2 < NCT) loadB(bA, ct + 2);
        compute(bB, ct + 1);
    }

    // reduce across the 16 column-lanes; waves own disjoint rows -> no LDS
#pragma unroll
    for (int m = 0; m < 2; ++m)
#pragma unroll
        for (int r = 0; r < 4; ++r) {
            float f = fs[m][r], g = ns[m][r];
#pragma unroll
            for (int msk = 1; msk < 16; msk <<= 1) {
                f += __shfl_xor(f, msk);
                g += __shfl_xor(g, msk);
            }
            if (l15 == 0) {
                int row = rowbase + wr * 32 + m * 16 + l4 * 4 + r;
                pf [ch * N2 + row] = f;
                png[ch * N2 + row] = g;
            }
        }
}

// ---- kernel 3: per-row loss + block partial -------------------------------
__global__ __launch_bounds__(256) void row_loss_k(
        const float* __restrict__ pf, const float* __restrict__ png,
        float* __restrict__ bpart)
{
    int row = blockIdx.x * 256 + threadIdx.x;
    float full = 0.f, ng = 0.f;
#pragma unroll
    for (int s = 0; s < NCHK; ++s) {
        full += pf[s * N2 + row];
        ng   += png[s * N2 + row];
    }
    float o1 = full - 0.9f * ng;                // (1 - tau+) = 0.9
    float o2 = full + 818.1f * ng;              // n*tau+ - (1-tau+) = 819 - 0.9
    float li = (__builtin_amdgcn_logf(o2) - __builtin_amdgcn_logf(o1)) * 0.6931471805599453f;

#pragma unroll
    for (int m = 1; m < 64; m <<= 1) li += __shfl_xor(li, m);
    __shared__ float red[4];
    if ((threadIdx.x & 63) == 0) red[threadIdx.x >> 6] = li;
    __syncthreads();
    if (threadIdx.x == 0) bpart[blockIdx.x] = red[0] + red[1] + red[2] + red[3];
}

// ---- kernel 4: final scalar ----------------------------------------------
__global__ void final_k(const float* __restrict__ bpart, float* __restrict__ out)
{
    int l = threadIdx.x;
    float v = (l < 32) ? bpart[l] : 0.f;
#pragma unroll
    for (int m = 1; m < 32; m <<= 1) v += __shfl_xor(v, m);
    if (l == 0) out[0] = v / (float)N2;
}

extern "C" void kernel_launch(void* const* d_in, const int* in_sizes, int n_in,
                              void* d_out, int out_size, void* d_ws, size_t ws_size,
                              hipStream_t stream)
{
    const float* out1 = (const float*)d_in[0];
    const float* out2 = (const float*)d_in[1];
    // d_in[2] = out_m, unused by the loss math
    const int*   tgt  = (const int*)d_in[3];
    float* out = (float*)d_out;

    // ws: obF8 1MB | pf 512KB | png 512KB | key 32KB | bpart 128B
    long*   obF  = (long*)d_ws;
    float*  pf   = (float*)((char*)d_ws + (1u << 20));
    float*  png  = (float*)((char*)d_ws + (1u << 20) + 524288);
    int*    key  = (int*)  ((char*)d_ws + (2u << 20));
    float*  bpart= (float*)((char*)d_ws + (2u << 20) + 32768);

    convert_k<<<512, 256, 0, stream>>>(out1, out2, tgt, obF, key);
    simloss_main<<<1024, 256, 0, stream>>>(obF, key, pf, png);
    row_loss_k<<<N2 / 256, 256, 0, stream>>>(pf, png, bpart);
    final_k<<<1, 64, 0, stream>>>(bpart, out);
}

// Round 15
// 39.150 us; speedup vs baseline: 5.1553x; 1.0491x over previous
//
#include <hip/hip_runtime.h>
#include <hip/hip_bf16.h>

typedef __attribute__((ext_vector_type(4))) float f32x4;

constexpr int BQ  = 4096;          // batch per view
constexpr int DD  = 128;           // dim
constexpr int N2  = 2 * BQ;        // 8192
constexpr int NCHK = 8;            // column chunks (1024 cols each)
constexpr int NCT  = 16;           // 64-col tiles per chunk
// exp(s/T) = exp2(s * 2/ln2); pre-scale matrix by sqrt(2.8853900817779268)
constexpr float SQS = 1.6986433f;

// ---- kernel 1: fp32 -> fp8(e4m3) in MFMA-fragment order, plus mask keys ----
// obF layout: frag(group,kk) = 64 lanes x 8 bytes at index (group*4+kk)*64+lane
// (long units). Lane l: row = group*16 + (l&15), k = kk*32 + (l>>4)*8 + j.
__global__ __launch_bounds__(256) void convert_k(const float* __restrict__ a,
        const float* __restrict__ b, const int* __restrict__ tgt,
        long* __restrict__ obF, int* __restrict__ key)
{
    int t = blockIdx.x * 256 + threadIdx.x;          // 131072 threads
    int row = t >> 4, c8 = t & 15;
    const float* src = (row < BQ) ? (a + (size_t)row * DD + c8 * 8)
                                  : (b + (size_t)(row - BQ) * DD + c8 * 8);
    float4 v0 = reinterpret_cast<const float4*>(src)[0];
    float4 v1 = reinterpret_cast<const float4*>(src)[1];
    int lo = __builtin_amdgcn_cvt_pk_fp8_f32(v0.x * SQS, v0.y * SQS, 0, false);
    lo     = __builtin_amdgcn_cvt_pk_fp8_f32(v0.z * SQS, v0.w * SQS, lo, true);
    int hi = __builtin_amdgcn_cvt_pk_fp8_f32(v1.x * SQS, v1.y * SQS, 0, false);
    hi     = __builtin_amdgcn_cvt_pk_fp8_f32(v1.z * SQS, v1.w * SQS, hi, true);
    long v = (((long)hi) << 32) | (unsigned)lo;
    int frag = ((row >> 4) * 4 + (c8 >> 2)) * 64 + (c8 & 3) * 16 + (row & 15);
    obF[frag] = v;

    if (t < N2) {
        // excl(i,j) == (key[i]==key[j]) covers BOTH the pair mask and the
        // target mask (rowmod==colmod implies identical target).
        int tv = tgt[t & (BQ - 1)];
        key[t] = (tv == -1) ? (0x40000000 + (t & (BQ - 1))) : tv;
    }
}

// ---- kernel 2: fused fp8 Gram + exp + mask + row sums ----------------------
// grid 512 = 64 row-tiles x 8 chunks; 256 thr = 4 waves (2wr x 2wc).
// Wave tile 64x32 per ct. B from L2 with 2-deep ping-pong register prefetch.
// KEY FIX vs R8: the mask keys ck(ct) are prefetched WITH loadB(ct) and
// carried in registers. Previously they were loaded inside compute(ct) as
// the NEWEST outstanding VMEM ops, so the epilogue's wait on them implied
// vmcnt(0) -- draining the just-issued next-tile B prefetch every iteration
// (prefetch structurally defeated -> the measured ~60% stall). Now each
// compute waits only on loads issued one full compute earlier: vmcnt stays
// high, L2 latency hidden even at 2 waves/SIMD.
__global__ __launch_bounds__(256, 3) void simloss_main(
        const long* __restrict__ F8, const int* __restrict__ key,
        float* __restrict__ pf, float* __restrict__ png)
{
    __shared__ float rred[2][128][2];    // row partials across wc

    const int tid  = threadIdx.x;
    const int lane = tid & 63;
    const int wid  = tid >> 6;
    const int wr   = wid >> 1;           // 0..1 (64-row half)
    const int wc   = wid & 1;            // 0..1 (32-col half)
    const int l15  = lane & 15;
    const int l4   = lane >> 4;

    // XCD swizzle: 512 blocks, ch == XCD -> each XCD reads one B chunk + A
    const int raw = blockIdx.x;
    const int bid = (raw & 7) * 64 + (raw >> 3);
    const int ch  = bid >> 6;            // 0..7
    const int rt  = bid & 63;            // 0..63
    const int rowbase = rt * 128;

    // A fragments: wave wr owns rows wr*64..wr*64+63 = groups rt*8+wr*4+m
    long af[4][4];
#pragma unroll
    for (int m = 0; m < 4; ++m)
#pragma unroll
        for (int kk = 0; kk < 4; ++kk)
            af[m][kk] = F8[((rt * 8 + wr * 4 + m) * 4 + kk) * 64 + lane];

    int rk[4][4];
#pragma unroll
    for (int m = 0; m < 4; ++m)
#pragma unroll
        for (int r = 0; r < 4; ++r)
            rk[m][r] = key[rowbase + wr * 64 + m * 16 + l4 * 4 + r];

    float fs[4][4] = {}, ns[4][4] = {};

    // B base for this wave: frag index (ch*256 + ct*16 + wc*8 + n*4 + kk)*64+lane
    const long* Bw = F8 + (size_t)(ch * 256 + wc * 8) * 64 + lane;
    const int*  kp = key + ch * 1024 + wc * 32 + l15;

    auto loadB = [&](long bx[8], int ct) {
        const long* p = Bw + ct * 1024;
#pragma unroll
        for (int q = 0; q < 8; ++q) bx[q] = p[q * 64];
    };
    auto compute = [&](const long bx[8], int ck0, int ck1) {
        f32x4 acc[4][2] = {};
#pragma unroll
        for (int kk = 0; kk < 4; ++kk)
#pragma unroll
            for (int m = 0; m < 4; ++m) {
                acc[m][0] = __builtin_amdgcn_mfma_f32_16x16x32_fp8_fp8(
                    af[m][kk], bx[kk], acc[m][0], 0, 0, 0);
                acc[m][1] = __builtin_amdgcn_mfma_f32_16x16x32_fp8_fp8(
                    af[m][kk], bx[4 + kk], acc[m][1], 0, 0, 0);
            }
#pragma unroll
        for (int m = 0; m < 4; ++m)
#pragma unroll
            for (int r = 0; r < 4; ++r) {
                float e0 = __builtin_amdgcn_exp2f(acc[m][0][r]);
                float e1 = __builtin_amdgcn_exp2f(acc[m][1][r]);
                fs[m][r] += e0 + e1;
                ns[m][r] += ((rk[m][r] == ck0) ? 0.0f : e0)
                          + ((rk[m][r] == ck1) ? 0.0f : e1);
            }
    };

    long bA[8], bB[8];
    int ckA0, ckA1, ckB0, ckB1;
    loadB(bA, 0);  ckA0 = kp[0];  ckA1 = kp[16];
#pragma unroll 1
    for (int ct = 0; ct < NCT; ct += 2) {
        // prefetch tile ct+1 (B frags AND its keys) before computing ct
        loadB(bB, ct + 1);
        ckB0 = kp[(ct + 1) * 64];
        ckB1 = kp[(ct + 1) * 64 + 16];
        compute(bA, ckA0, ckA1);
        if (ct + 2 < NCT) {
            loadB(bA, ct + 2);
            ckA0 = kp[(ct + 2) * 64];
            ckA1 = kp[(ct + 2) * 64 + 16];
        }
        compute(bB, ckB0, ckB1);
    }

    // reduce across the 16 column-lanes, combine wc halves via LDS
#pragma unroll
    for (int m = 0; m < 4; ++m)
#pragma unroll
        for (int r = 0; r < 4; ++r) {
            float f = fs[m][r], g = ns[m][r];
#pragma unroll
            for (int msk = 1; msk < 16; msk <<= 1) {
                f += __shfl_xor(f, msk);
                g += __shfl_xor(g, msk);
            }
            if (l15 == 0) {
                int rl = wr * 64 + m * 16 + l4 * 4 + r;
                rred[wc][rl][0] = f;
                rred[wc][rl][1] = g;
            }
        }
    __syncthreads();
    if (tid < 128) {
        pf [ch * N2 + rowbase + tid] = rred[0][tid][0] + rred[1][tid][0];
        png[ch * N2 + rowbase + tid] = rred[0][tid][1] + rred[1][tid][1];
    }
}

// ---- kernel 3: per-row loss + block partial -------------------------------
__global__ __launch_bounds__(256) void row_loss_k(
        const float* __restrict__ pf, const float* __restrict__ png,
        float* __restrict__ bpart)
{
    int row = blockIdx.x * 256 + threadIdx.x;
    float full = 0.f, ng = 0.f;
#pragma unroll
    for (int s = 0; s < NCHK; ++s) {
        full += pf[s * N2 + row];
        ng   += png[s * N2 + row];
    }
    float o1 = full - 0.9f * ng;                // (1 - tau+) = 0.9
    float o2 = full + 818.1f * ng;              // n*tau+ - (1-tau+) = 819 - 0.9
    float li = (__builtin_amdgcn_logf(o2) - __builtin_amdgcn_logf(o1)) * 0.6931471805599453f;

#pragma unroll
    for (int m = 1; m < 64; m <<= 1) li += __shfl_xor(li, m);
    __shared__ float red[4];
    if ((threadIdx.x & 63) == 0) red[threadIdx.x >> 6] = li;
    __syncthreads();
    if (threadIdx.x == 0) bpart[blockIdx.x] = red[0] + red[1] + red[2] + red[3];
}

// ---- kernel 4: final scalar ----------------------------------------------
__global__ void final_k(const float* __restrict__ bpart, float* __restrict__ out)
{
    int l = threadIdx.x;
    float v = (l < 32) ? bpart[l] : 0.f;
#pragma unroll
    for (int m = 1; m < 32; m <<= 1) v += __shfl_xor(v, m);
    if (l == 0) out[0] = v / (float)N2;
}

extern "C" void kernel_launch(void* const* d_in, const int* in_sizes, int n_in,
                              void* d_out, int out_size, void* d_ws, size_t ws_size,
                              hipStream_t stream)
{
    const float* out1 = (const float*)d_in[0];
    const float* out2 = (const float*)d_in[1];
    // d_in[2] = out_m, unused by the loss math
    const int*   tgt  = (const int*)d_in[3];
    float* out = (float*)d_out;

    // ws: obF8 1MB | pf 256KB | png 256KB | key 32KB | bpart 128B
    long*   obF  = (long*)d_ws;
    float*  pf   = (float*)((char*)d_ws + (1u << 20));
    float*  png  = (float*)((char*)d_ws + (1u << 20) + 262144);
    int*    key  = (int*)  ((char*)d_ws + (1u << 20) + 524288);
    float*  bpart= (float*)((char*)d_ws + (1u << 20) + 524288 + 32768);

    convert_k<<<512, 256, 0, stream>>>(out1, out2, tgt, obF, key);
    simloss_main<<<512, 256, 0, stream>>>(obF, key, pf, png);
    row_loss_k<<<N2 / 256, 256, 0, stream>>>(pf, png, bpart);
    final_k<<<1, 64, 0, stream>>>(bpart, out);
}